// Round 8
// baseline (399.140 us; speedup 1.0000x reference)
//
#include <hip/hip_runtime.h>
#include <math.h>

#define HEAD_DIM 256
#define N_Q 8
#define N_KV 4
#define HIDDEN 2304
#define WINDOW 1024
#define BATCH 2
#define SEQ 2048
#define BT (BATCH*SEQ)      // 4096 rows total

typedef unsigned short u16;
typedef __attribute__((ext_vector_type(8))) short bf16x8;
typedef __attribute__((ext_vector_type(4))) float f32x4;

__device__ __forceinline__ u16 f2bf(float f) {
    union { float f; unsigned u; } c; c.f = f;
    unsigned r = c.u + 0x7FFF + ((c.u >> 16) & 1);   // RNE
    return (u16)(r >> 16);
}
__device__ __forceinline__ float bf2f(u16 b) {
    union { float f; unsigned u; } c; c.u = ((unsigned)b) << 16;
    return c.f;
}

// ---------------------------------------------------------------------------
// Fused preprocessing: convert_x (blocks 0..4607) | wqkv_t (4608..6911) |
// wo_t (6912..8063).
// ---------------------------------------------------------------------------
__global__ __launch_bounds__(256) void prep_kernel(
    const float* __restrict__ x,
    const float* __restrict__ Wq, const float* __restrict__ Wk,
    const float* __restrict__ Wv, const float* __restrict__ Wo,
    u16* __restrict__ xb, u16* __restrict__ wt1, u16* __restrict__ wot)
{
    __shared__ float t[64][65];
    const int bx  = blockIdx.x;
    const int tid = threadIdx.x;

    if (bx < 4608) {
        const int i = bx * 256 + tid;
        const float4 a = ((const float4*)x)[2*i];
        const float4 b = ((const float4*)x)[2*i+1];
        u16 o[8] = { f2bf(a.x), f2bf(a.y), f2bf(a.z), f2bf(a.w),
                     f2bf(b.x), f2bf(b.y), f2bf(b.z), f2bf(b.w) };
        ((uint4*)xb)[i] = *(const uint4*)o;
        return;
    }

    if (bx < 6912) {
        const int b   = bx - 4608;
        const int j   = b / 144;
        const int rem = b % 144;
        const int d0  = (rem % 36) * 64;
        const int h0  = (rem / 36) * 64;
        const float* W = (j < 8)  ? Wq + (size_t)j*HIDDEN*HEAD_DIM
                       : (j < 12) ? Wk + (size_t)(j-8)*HIDDEN*HEAD_DIM
                                  : Wv + (size_t)(j-12)*HIDDEN*HEAD_DIM;
        {
            const int r = tid >> 4, c4 = tid & 15;
            #pragma unroll
            for (int rr = r; rr < 64; rr += 16) {
                const float4 v = *(const float4*)(W + (size_t)(d0+rr)*HEAD_DIM + h0 + c4*4);
                t[rr][c4*4+0] = v.x; t[rr][c4*4+1] = v.y;
                t[rr][c4*4+2] = v.z; t[rr][c4*4+3] = v.w;
            }
        }
        __syncthreads();
        {
            const int hh = tid >> 2;
            #pragma unroll
            for (int it = 0; it < 2; it++) {
                const int chunk = (tid & 3) + it*4;
                u16 tmp[8];
                #pragma unroll
                for (int jj = 0; jj < 8; jj++) tmp[jj] = f2bf(t[chunk*8+jj][hh]);
                *(uint4*)&wt1[(size_t)(j*256 + h0 + hh)*HIDDEN + d0 + chunk*8] = *(const uint4*)tmp;
            }
        }
        return;
    }

    {
        const int b  = bx - 6912;
        const int k0 = (b & 31) * 64;
        const int d0 = (b >> 5) * 64;
        {
            const int r = tid >> 4, c4 = tid & 15;
            #pragma unroll
            for (int rr = r; rr < 64; rr += 16) {
                const float4 v = *(const float4*)(Wo + (size_t)(k0+rr)*HIDDEN + d0 + c4*4);
                t[rr][c4*4+0] = v.x; t[rr][c4*4+1] = v.y;
                t[rr][c4*4+2] = v.z; t[rr][c4*4+3] = v.w;
            }
        }
        __syncthreads();
        {
            const int dd = tid >> 2;
            #pragma unroll
            for (int it = 0; it < 2; it++) {
                const int chunk = (tid & 3) + it*4;
                u16 tmp[8];
                #pragma unroll
                for (int jj = 0; jj < 8; jj++) tmp[jj] = f2bf(t[chunk*8+jj][dd]);
                *(uint4*)&wot[(size_t)(d0 + dd)*(N_Q*HEAD_DIM) + k0 + chunk*8] = *(const uint4*)tmp;
            }
        }
    }
}

// ---------------------------------------------------------------------------
// 256x256 bf16 GEMM, 4-phase double-K-step (R8).
//
// Cycle accounting across R2-R7 (5 schedule variants, all 37-39% MfmaUtil):
// measured double-step = 10904 cyc = MFMA 4966 + LDS-serial 3000 + 16 barrier
// events x ~180 cyc. The residual scales with EVENT COUNT, not schedule
// order (why all variants tied). m201's 62% = the same serial model with
// zero event residual. This version halves events: merge mh0/mh1 phases ->
// 4 phases/double-step, each {12 ds_read -> BAR -> 32 MFMA -> BAR}, 8
// barriers + 2 waits instead of 16 + 2.
//
// Staging ledger (iter t reads tiles 2t (buf0, NP1/2), 2t+1 (buf1, NP3/4);
// stages T2=2t+2 -> buf0, T3=2t+3 -> buf1; 16 calls/iter):
//   NP2-mid : B of T2  (4 calls)   [after BAR#1 -> all buf0 reads issued]
//   NP3-top : A of T2  (4 calls)
//   NP4-mid : B+A of T3 (8 calls)  [after BAR#1 -> all buf1 reads issued]
// Waits:
//   NP2-end WAITV(4): retires tile(2t+1)'s 8 (staged prev NP4-mid) -> buf1
//     complete before NP3 reads. Keeps B-of-T2 (4). Cover >= 2 phases.
//   NP4-end WAITV(8): retires B+A of T2 -> buf0 complete before next NP1.
//     Keeps T3's 8. Cover >= 1 phase (NP3-top's A-T2).
// Prologue: tile0+tile1 (16 calls), WAITV(8) -> entering steady invariant
// (tile1's 8 outstanding). Last iter: T2/T3 suppressed; NP2-end WAITV(0).
// ---------------------------------------------------------------------------
template<int KK>
__device__ __forceinline__ void g256_ld_b(const u16 (&BsB)[16384], bf16x8 (&bf)[4],
                                          int wcol, int l16, int quad, int axor)
{
    #pragma unroll
    for (int j = 0; j < 4; j++)
        bf[j] = *(const bf16x8*)(&BsB[(wcol*64 + j*16 + l16)*64 + (((KK<<2)|quad)^axor)*8]);
}
template<int KK>
__device__ __forceinline__ void g256_ld_a8(const u16 (&AsB)[16384], bf16x8 (&af)[8],
                                           int wrow, int l16, int quad, int axor)
{
    #pragma unroll
    for (int i = 0; i < 8; i++)
        af[i] = *(const bf16x8*)(&AsB[(wrow*128 + i*16 + l16)*64 + (((KK<<2)|quad)^axor)*8]);
}
__device__ __forceinline__ void g256_mfma32(const bf16x8 (&af)[8], const bf16x8 (&bf)[4],
                                            f32x4 (&acc)[8][4])
{
    __builtin_amdgcn_s_setprio(1);
    #pragma unroll
    for (int i = 0; i < 8; i++)
        #pragma unroll
        for (int j = 0; j < 4; j++)
            acc[i][j] = __builtin_amdgcn_mfma_f32_16x16x32_bf16(
                            af[i], bf[j], acc[i][j], 0, 0, 0);
    __builtin_amdgcn_s_setprio(0);
}

// one call = 64 rows (8 waves x 8 rows), 16 B/lane, vmcnt +1 per thread.
#define STG256(DST, SRCP, R0, KT)                                              \
    __builtin_amdgcn_global_load_lds(                                          \
        (const __attribute__((address_space(1))) unsigned int*)                \
            ((SRCP) + (size_t)(R0)*K + (size_t)(KT)*64),                       \
        (__attribute__((address_space(3))) unsigned int*)                      \
            (&DST[((R0) + wave*8)*64]),                                        \
        16, 0, 0)

#define WAITV(N) asm volatile("s_waitcnt vmcnt(" #N ")" ::: "memory")
#define BAR()    __builtin_amdgcn_s_barrier()

template<typename OutT>
__global__ __launch_bounds__(512, 2) void gemm256_kernel(
    const u16* __restrict__ A, const u16* __restrict__ Bt,
    OutT* __restrict__ C, int M, int N, int K)
{
    __shared__ __align__(16) u16 As0[16384];   // [256 rows][64], buf0
    __shared__ __align__(16) u16 As1[16384];   // buf1
    __shared__ __align__(16) u16 Bs0[16384];
    __shared__ __align__(16) u16 Bs1[16384];

    // bijective XCD swizzle (nwg % 8 == 0 for both call sites)
    const int nwg = gridDim.x;
    const int bid = blockIdx.x;
    const int cpx = nwg >> 3;
    const int swz = (bid & 7) * cpx + (bid >> 3);
    const int NX  = N >> 8;
    const int m0  = (swz / NX) << 8;
    const int n0  = (swz % NX) << 8;

    const int tid  = threadIdx.x;
    const int lane = tid & 63;
    const int wave = tid >> 6;
    const int wrow = wave >> 2;          // 0..1
    const int wcol = wave & 3;           // 0..3
    const int l16  = lane & 15;
    const int quad = lane >> 4;
    const int axor = l16 & 7;

    const int srow8  = lane >> 3;
    const int schunk = (lane & 7) ^ srow8;      // pre-swizzled DMA source chunk
    const u16* Ag = A  + (size_t)(m0 + wave*8 + srow8)*K + schunk*8;
    const u16* Bg = Bt + (size_t)(n0 + wave*8 + srow8)*K + schunk*8;

    f32x4 acc[8][4];
    #pragma unroll
    for (int i = 0; i < 8; i++)
        #pragma unroll
        for (int j = 0; j < 4; j++) acc[i][j] = (f32x4){0.f,0.f,0.f,0.f};
    bf16x8 af[8], bf[4];

    // prologue: tile0 -> buf0 (8 calls), tile1 -> buf1 (8 calls)
    STG256(Bs0, Bg,   0, 0); STG256(Bs0, Bg,  64, 0);
    STG256(Bs0, Bg, 128, 0); STG256(Bs0, Bg, 192, 0);
    STG256(As0, Ag,   0, 0); STG256(As0, Ag,  64, 0);
    STG256(As0, Ag, 128, 0); STG256(As0, Ag, 192, 0);
    STG256(Bs1, Bg,   0, 1); STG256(Bs1, Bg,  64, 1);
    STG256(Bs1, Bg, 128, 1); STG256(Bs1, Bg, 192, 1);
    STG256(As1, Ag,   0, 1); STG256(As1, Ag,  64, 1);
    STG256(As1, Ag, 128, 1); STG256(As1, Ag, 192, 1);
    WAITV(8);                 // tile0 landed; tile1's 8 in flight (invariant)
    BAR();

    const int NT2 = K >> 7;          // K/128 double-K-tile iterations
    for (int t = 0; t < NT2; ++t) {
        const int T2 = 2*t+2, T3 = 2*t+3;
        const bool nl = (t < NT2-1);

        // ---- NP1: buf0 kk0 (mh0+mh1, 32 MFMA) ----
        g256_ld_b<0>(Bs0, bf, wcol, l16, quad, axor);
        g256_ld_a8<0>(As0, af, wrow, l16, quad, axor);
        BAR();
        g256_mfma32(af, bf, acc);
        BAR();

        // ---- NP2: buf0 kk1; mid-stage B of T2; end-wait for buf1 ----
        g256_ld_b<1>(Bs0, bf, wcol, l16, quad, axor);
        g256_ld_a8<1>(As0, af, wrow, l16, quad, axor);
        BAR();
        if (nl) { STG256(Bs0, Bg, 0, T2); STG256(Bs0, Bg, 64, T2);
                  STG256(Bs0, Bg, 128, T2); STG256(Bs0, Bg, 192, T2); }
        g256_mfma32(af, bf, acc);
        if (nl) { WAITV(4); }        // retires tile(2t+1)'s 8 -> buf1 ready
        else    { WAITV(0); }
        BAR();

        // ---- NP3: buf1 kk0; top-stage A of T2 ----
        g256_ld_b<0>(Bs1, bf, wcol, l16, quad, axor);
        g256_ld_a8<0>(As1, af, wrow, l16, quad, axor);
        if (nl) { STG256(As0, Ag, 0, T2); STG256(As0, Ag, 64, T2);
                  STG256(As0, Ag, 128, T2); STG256(As0, Ag, 192, T2); }
        BAR();
        g256_mfma32(af, bf, acc);
        BAR();

        // ---- NP4: buf1 kk1; mid-stage B+A of T3; end-wait for buf0 ----
        g256_ld_b<1>(Bs1, bf, wcol, l16, quad, axor);
        g256_ld_a8<1>(As1, af, wrow, l16, quad, axor);
        BAR();
        if (nl) { STG256(Bs1, Bg, 0, T3); STG256(Bs1, Bg, 64, T3);
                  STG256(Bs1, Bg, 128, T3); STG256(Bs1, Bg, 192, T3);
                  STG256(As1, Ag, 0, T3); STG256(As1, Ag, 64, T3);
                  STG256(As1, Ag, 128, T3); STG256(As1, Ag, 192, T3); }
        g256_mfma32(af, bf, acc);
        if (nl) { WAITV(8); }        // retires B+A of T2 -> buf0 ready
        BAR();
    }

    #pragma unroll
    for (int ii = 0; ii < 8; ii++) {
        const int rbase = m0 + wrow*128 + ii*16 + quad*4;
        #pragma unroll
        for (int j = 0; j < 4; j++) {
            const int col = n0 + wcol*64 + j*16 + l16;
            #pragma unroll
            for (int r = 0; r < 4; r++) {
                const float v = acc[ii][j][r];
                if constexpr (sizeof(OutT) == 2)
                    ((u16*)C)[(size_t)(rbase + r)*N + col] = f2bf(v);
                else
                    ((float*)C)[(size_t)(rbase + r)*N + col] = v;
            }
        }
    }
}

#undef STG256

// ---------------------------------------------------------------------------
// Fused RoPE (blocks 0..4095) + V-transpose (4096..4607).
// ---------------------------------------------------------------------------
__global__ __launch_bounds__(256) void ropevt_kernel(
    const u16* __restrict__ raw, u16* __restrict__ qb,
    u16* __restrict__ kbf, u16* __restrict__ vtt)
{
    __shared__ u16 T[32*264];
    const int bx  = blockIdx.x;
    const int tid = threadIdx.x;

    if (bx < BT) {
        const int r   = bx;
        const int pos = r & (SEQ-1);
        const u16* row = raw + (size_t)r * 4096;
        const float LOG1E4 = 9.210340371976184f;

        #pragma unroll
        for (int p = tid; p < 1024; p += 256) {   // q pairs
            const int n = p >> 7, j = p & 127;
            const float lo = bf2f(row[n*256 + j]);
            const float hi = bf2f(row[n*256 + j + 128]);
            const float inv = __expf(-LOG1E4 * (float)j * (1.0f/128.0f));
            float s, c; sincosf((float)pos * inv, &s, &c);
            qb[((size_t)r*N_Q + n)*HEAD_DIM + j]       = f2bf((lo*c - hi*s) * 0.0625f);
            qb[((size_t)r*N_Q + n)*HEAD_DIM + j + 128] = f2bf((hi*c + lo*s) * 0.0625f);
        }
        #pragma unroll
        for (int p = tid; p < 512; p += 256) {    // k pairs
            const int n = p >> 7, j = p & 127;
            const float lo = bf2f(row[2048 + n*256 + j]);
            const float hi = bf2f(row[2048 + n*256 + j + 128]);
            const float inv = __expf(-LOG1E4 * (float)j * (1.0f/128.0f));
            float s, c; sincosf((float)pos * inv, &s, &c);
            kbf[((size_t)r*N_KV + n)*HEAD_DIM + j]       = f2bf(lo*c - hi*s);
            kbf[((size_t)r*N_KV + n)*HEAD_DIM + j + 128] = f2bf(hi*c + lo*s);
        }
        return;
    }

    {
        const int blk = bx - BT;
        const int sc  = blk & 63;
        const int bk  = blk >> 6;
        const int b   = bk >> 2, kh = bk & 3;

        const u16* rrow = raw + (size_t)(b*SEQ + sc*32)*4096 + 3072 + kh*256;
        {
            const int s = tid >> 3;
            #pragma unroll
            for (int it = 0; it < 4; it++) {
                const int seg = (tid & 7) + it*8;
                *(uint4*)&T[s*264 + seg*8] = *(const uint4*)(rrow + (size_t)s*4096 + seg*8);
            }
        }
        __syncthreads();
        u16* out = vtt + (size_t)blk*8192;
        #pragma unroll
        for (int it = 0; it < 4; it++) {
            const int o = tid + it*256;
            const int h = o >> 2, ss = o & 3;
            u16 tmp[8];
            #pragma unroll
            for (int j = 0; j < 8; j++) tmp[j] = T[(ss*8 + j)*264 + h];
            *(uint4*)(out + h*32 + ((ss ^ (h & 3))*8)) = *(const uint4*)tmp;
        }
    }
}

// ---------------------------------------------------------------------------
// MFMA flash attention, fixed-max softmax (unchanged).
// ---------------------------------------------------------------------------
#define AQT 64
__global__ __launch_bounds__(256) void attn_mfma_kernel(
    const u16* __restrict__ qb, const u16* __restrict__ kb,
    const u16* __restrict__ vtt, u16* __restrict__ ao)
{
    __shared__ u16 Ks[32*264];    // K[s][d], pad 264
    __shared__ u16 Vs[256*32];    // V^T[h][s-chunks swizzled], unpadded (DMA)
    __shared__ u16 Ps[64*40];     // P[t][s], pad 40
    __shared__ float lsum[64];

    const int qh = blockIdx.y;
    const int kh = qh >> 1;
    const int bx = ((blockIdx.y >> 2) & 1) ? (gridDim.x - 1 - (int)blockIdx.x)
                                           : (int)blockIdx.x;
    const int t0 = bx * AQT;
    const int b  = t0 >> 11;
    const int tb = t0 & (SEQ-1);
    const int tid  = threadIdx.x;
    const int wave = tid >> 6;
    const int lane = tid & 63;
    const int l16  = lane & 15;
    const int quad = lane >> 4;

    bf16x8 qf[8];
    {
        const u16* qrow = qb + ((size_t)(t0 + wave*16 + l16)*N_Q + qh)*HEAD_DIM + quad*8;
        #pragma unroll
        for (int c = 0; c < 8; c++) qf[c] = *(const bf16x8*)(qrow + c*32);
    }

    f32x4 o[4][4];
    #pragma unroll
    for (int i = 0; i < 4; i++)
        #pragma unroll
        for (int j = 0; j < 4; j++) o[i][j] = (f32x4){0.f,0.f,0.f,0.f};
    float lpart[4] = {0.f, 0.f, 0.f, 0.f};

    int s_begin = tb - (WINDOW-1); if (s_begin < 0) s_begin = 0;
    const int st0 = s_begin & ~31;

    const u16* kbase = kb  + ((size_t)(b*SEQ)*N_KV + kh)*HEAD_DIM;
    const u16* vbase = vtt + ((size_t)(b*N_KV + kh)*SEQ)*HEAD_DIM;

    for (int st = st0; st < tb + AQT; st += 32) {
        __syncthreads();
        {   // V tile via DMA: 16 KB contiguous, 4 calls/wave
            const u16* vtile = vbase + (size_t)st*HEAD_DIM;
            #pragma unroll
            for (int c = 0; c < 4; c++) {
                const int off = wave*2048 + c*512;
                __builtin_amdgcn_global_load_lds(
                    (const __attribute__((address_space(1))) unsigned int*)(vtile + off + lane*8),
                    (__attribute__((address_space(3))) unsigned int*)&Vs[off],
                    16, 0, 0);
            }
            // K tile manual (padded 264)
            const int s = tid >> 3;
            const u16* krow = kbase + (size_t)(st + s)*(N_KV*HEAD_DIM);
            #pragma unroll
            for (int it = 0; it < 4; it++) {
                const int seg = (tid & 7) + it*8;
                *(uint4*)&Ks[s*264 + seg*8] = *(const uint4*)(krow + seg*8);
            }
        }
        __syncthreads();

        // QK^T: wave rows wave*16..+15, S[16][32]
        f32x4 sc[2];
        #pragma unroll
        for (int sf = 0; sf < 2; sf++) {
            f32x4 a = (f32x4){0.f,0.f,0.f,0.f};
            const u16* kr = &Ks[(sf*16 + l16)*264 + quad*8];
            #pragma unroll
            for (int c = 0; c < 8; c++)
                a = __builtin_amdgcn_mfma_f32_16x16x32_bf16(
                        qf[c], *(const bf16x8*)(kr + c*32), a, 0, 0, 0);
            sc[sf] = a;
        }

        // fused soft-cap + fixed-max softmax, write P
        #pragma unroll
        for (int sf = 0; sf < 2; sf++) {
            const int sg = st + sf*16 + l16;
            #pragma unroll
            for (int r = 0; r < 4; r++) {
                const int tg = tb + wave*16 + quad*4 + r;
                const float e1 = __expf(sc[sf][r] * 0.04f);       // e^{S/25}
                float p = __expf(-100.0f / (e1 + 1.0f));          // exp(cap-50)
                const bool ok = (sg <= tg) && (tg - sg < WINDOW);
                p = ok ? p : 0.0f;
                lpart[r] += p;
                Ps[(wave*16 + quad*4 + r)*40 + sf*16 + l16] = f2bf(p);
            }
        }
        __syncthreads();   // Ps complete (all 64 rows)

        // PV: wave owns h-cols wave*64..+63, all 64 rows
        bf16x8 ap[4];
        #pragma unroll
        for (int i = 0; i < 4; i++)
            ap[i] = *(const bf16x8*)&Ps[(i*16 + l16)*40 + quad*8];
        #pragma unroll
        for (int j = 0; j < 4; j++) {
            const int hr = wave*64 + j*16 + l16;
            const bf16x8 bv = *(const bf16x8*)&Vs[hr*32 + ((quad ^ (l16 & 3))*8)];
            #pragma unroll
            for (int i = 0; i < 4; i++)
                o[i][j] = __builtin_amdgcn_mfma_f32_16x16x32_bf16(ap[i], bv, o[i][j], 0, 0, 0);
        }
    }

    // row sums -> LDS (QK rows are wave-owned)
    #pragma unroll
    for (int r = 0; r < 4; r++) {
        float s = lpart[r];
        #pragma unroll
        for (int sh = 1; sh <= 8; sh <<= 1) s += __shfl_xor(s, sh, 64);
        if (l16 == 0) lsum[wave*16 + quad*4 + r] = s;
    }
    __syncthreads();

    #pragma unroll
    for (int i = 0; i < 4; i++) {
        #pragma unroll
        for (int r = 0; r < 4; r++) {
            const int rl  = i*16 + quad*4 + r;
            const float inv = 1.0f / (lsum[rl] + 1e-30f);
            u16* arow = ao + ((size_t)(t0 + rl)*N_Q + qh)*HEAD_DIM + wave*64 + l16;
            #pragma unroll
            for (int j = 0; j < 4; j++)
                arow[j*16] = f2bf(o[i][j][r] * inv);
        }
    }
}

// ---------------------------------------------------------------------------
extern "C" void kernel_launch(void* const* d_in, const int* in_sizes, int n_in,
                              void* d_out, int out_size, void* d_ws, size_t ws_size,
                              hipStream_t stream)
{
    const float* x  = (const float*)d_in[0];
    // d_in[1] = attention_mask: exactly causal(tril) -> not needed.
    const float* Wq = (const float*)d_in[2];
    const float* Wk = (const float*)d_in[3];
    const float* Wv = (const float*)d_in[4];
    const float* Wo = (const float*)d_in[5];
    float* out = (float*)d_out;

    char* w = (char*)d_ws;
    u16* qbuf = (u16*)(w);                     // 16,777,216
    u16* kbuf = (u16*)(w +  16777216ull);      //  8,388,608
    u16* vtt  = (u16*)(w +  25165824ull);      //  8,388,608
    u16* aob  = (u16*)(w +  33554432ull);      // 16,777,216
    u16* xb   = (u16*)(w +  50331648ull);      // 18,874,368
    u16* wt1  = (u16*)(w +  69206016ull);      // 18,874,368
    u16* wot  = (u16*)(w +  88080384ull);      //  9,437,184
    u16* raw  = (u16*)(w +  97517568ull);      // 33,554,432 (end ~131 MB)

    // 1) fused preprocessing
    prep_kernel<<<8064, 256, 0, stream>>>(x, Wq, Wk, Wv, Wo, xb, wt1, wot);

    // 2) QKV GEMM: 256x256 4-phase, 256 blocks = 1/CU.
    gemm256_kernel<u16><<<(BT/256)*(4096/256), 512, 0, stream>>>(
        xb, wt1, raw, BT, 4096, HIDDEN);

    // 3) fused RoPE + V-transpose
    ropevt_kernel<<<BT + BATCH*N_KV*64, 256, 0, stream>>>(raw, qbuf, kbuf, vtt);

    // 4) attention
    attn_mfma_kernel<<<dim3(BT/AQT, N_Q), 256, 0, stream>>>(qbuf, kbuf, vtt, aob);

    // 5) output GEMM: 16x9 = 144 blocks (cpx=18, bijective swizzle holds).
    gemm256_kernel<float><<<(BT/256)*(HIDDEN/256), 512, 0, stream>>>(
        aob, wot, out, BT, HIDDEN, N_Q*HEAD_DIM);
}

// Round 9
// 383.374 us; speedup vs baseline: 1.0411x; 1.0411x over previous
//
#include <hip/hip_runtime.h>
#include <math.h>

#define HEAD_DIM 256
#define N_Q 8
#define N_KV 4
#define HIDDEN 2304
#define WINDOW 1024
#define BATCH 2
#define SEQ 2048
#define BT (BATCH*SEQ)      // 4096 rows total

typedef unsigned short u16;
typedef __attribute__((ext_vector_type(8))) short bf16x8;
typedef __attribute__((ext_vector_type(4))) float f32x4;

__device__ __forceinline__ u16 f2bf(float f) {
    union { float f; unsigned u; } c; c.f = f;
    unsigned r = c.u + 0x7FFF + ((c.u >> 16) & 1);   // RNE
    return (u16)(r >> 16);
}
__device__ __forceinline__ float bf2f(u16 b) {
    union { float f; unsigned u; } c; c.u = ((unsigned)b) << 16;
    return c.f;
}

// ---------------------------------------------------------------------------
// Fused preprocessing: convert_x (blocks 0..4607) | wqkv_t (4608..6911) |
// wo_t (6912..8063).
// ---------------------------------------------------------------------------
__global__ __launch_bounds__(256) void prep_kernel(
    const float* __restrict__ x,
    const float* __restrict__ Wq, const float* __restrict__ Wk,
    const float* __restrict__ Wv, const float* __restrict__ Wo,
    u16* __restrict__ xb, u16* __restrict__ wt1, u16* __restrict__ wot)
{
    __shared__ float t[64][65];
    const int bx  = blockIdx.x;
    const int tid = threadIdx.x;

    if (bx < 4608) {
        const int i = bx * 256 + tid;
        const float4 a = ((const float4*)x)[2*i];
        const float4 b = ((const float4*)x)[2*i+1];
        u16 o[8] = { f2bf(a.x), f2bf(a.y), f2bf(a.z), f2bf(a.w),
                     f2bf(b.x), f2bf(b.y), f2bf(b.z), f2bf(b.w) };
        ((uint4*)xb)[i] = *(const uint4*)o;
        return;
    }

    if (bx < 6912) {
        const int b   = bx - 4608;
        const int j   = b / 144;
        const int rem = b % 144;
        const int d0  = (rem % 36) * 64;
        const int h0  = (rem / 36) * 64;
        const float* W = (j < 8)  ? Wq + (size_t)j*HIDDEN*HEAD_DIM
                       : (j < 12) ? Wk + (size_t)(j-8)*HIDDEN*HEAD_DIM
                                  : Wv + (size_t)(j-12)*HIDDEN*HEAD_DIM;
        {
            const int r = tid >> 4, c4 = tid & 15;
            #pragma unroll
            for (int rr = r; rr < 64; rr += 16) {
                const float4 v = *(const float4*)(W + (size_t)(d0+rr)*HEAD_DIM + h0 + c4*4);
                t[rr][c4*4+0] = v.x; t[rr][c4*4+1] = v.y;
                t[rr][c4*4+2] = v.z; t[rr][c4*4+3] = v.w;
            }
        }
        __syncthreads();
        {
            const int hh = tid >> 2;
            #pragma unroll
            for (int it = 0; it < 2; it++) {
                const int chunk = (tid & 3) + it*4;
                u16 tmp[8];
                #pragma unroll
                for (int jj = 0; jj < 8; jj++) tmp[jj] = f2bf(t[chunk*8+jj][hh]);
                *(uint4*)&wt1[(size_t)(j*256 + h0 + hh)*HIDDEN + d0 + chunk*8] = *(const uint4*)tmp;
            }
        }
        return;
    }

    {
        const int b  = bx - 6912;
        const int k0 = (b & 31) * 64;
        const int d0 = (b >> 5) * 64;
        {
            const int r = tid >> 4, c4 = tid & 15;
            #pragma unroll
            for (int rr = r; rr < 64; rr += 16) {
                const float4 v = *(const float4*)(Wo + (size_t)(k0+rr)*HIDDEN + d0 + c4*4);
                t[rr][c4*4+0] = v.x; t[rr][c4*4+1] = v.y;
                t[rr][c4*4+2] = v.z; t[rr][c4*4+3] = v.w;
            }
        }
        __syncthreads();
        {
            const int dd = tid >> 2;
            #pragma unroll
            for (int it = 0; it < 2; it++) {
                const int chunk = (tid & 3) + it*4;
                u16 tmp[8];
                #pragma unroll
                for (int jj = 0; jj < 8; jj++) tmp[jj] = f2bf(t[chunk*8+jj][dd]);
                *(uint4*)&wot[(size_t)(d0 + dd)*(N_Q*HEAD_DIM) + k0 + chunk*8] = *(const uint4*)tmp;
            }
        }
    }
}

// ---------------------------------------------------------------------------
// 256x256 8-phase bf16 GEMM — EXACT R3 schedule (best of 6 measured variants:
// 82 us QKV, MfmaUtil 38.5%, 0 bank conflicts). R4/R5 (read-ahead), R7
// (2 blocks/CU), R8 (4-phase merge) all regressed or tied. FROZEN.
// ---------------------------------------------------------------------------
template<int KK>
__device__ __forceinline__ void g256_ld_b(const u16 (&BsB)[16384], bf16x8 (&bf)[4],
                                          int wcol, int l16, int quad, int axor)
{
    #pragma unroll
    for (int j = 0; j < 4; j++)
        bf[j] = *(const bf16x8*)(&BsB[(wcol*64 + j*16 + l16)*64 + (((KK<<2)|quad)^axor)*8]);
}
template<int MH, int KK>
__device__ __forceinline__ void g256_ld_a(const u16 (&AsB)[16384], bf16x8 (&af)[4],
                                          int wrow, int l16, int quad, int axor)
{
    #pragma unroll
    for (int i = 0; i < 4; i++)
        af[i] = *(const bf16x8*)(&AsB[(wrow*128 + MH*64 + i*16 + l16)*64 + (((KK<<2)|quad)^axor)*8]);
}
template<int MH>
__device__ __forceinline__ void g256_mfma(const bf16x8 (&af)[4], const bf16x8 (&bf)[4],
                                          f32x4 (&acc)[8][4])
{
    __builtin_amdgcn_s_setprio(1);
    #pragma unroll
    for (int i = 0; i < 4; i++)
        #pragma unroll
        for (int j = 0; j < 4; j++)
            acc[MH*4+i][j] = __builtin_amdgcn_mfma_f32_16x16x32_bf16(
                                 af[i], bf[j], acc[MH*4+i][j], 0, 0, 0);
    __builtin_amdgcn_s_setprio(0);
}

// one call = 64 rows (8 waves x 8 rows), 16 B/lane, vmcnt +1 per thread.
#define STG256(DST, SRCP, R0, KT)                                              \
    __builtin_amdgcn_global_load_lds(                                          \
        (const __attribute__((address_space(1))) unsigned int*)                \
            ((SRCP) + (size_t)(R0)*K + (size_t)(KT)*64),                       \
        (__attribute__((address_space(3))) unsigned int*)                      \
            (&DST[((R0) + wave*8)*64]),                                        \
        16, 0, 0)

#define WAITV(N) asm volatile("s_waitcnt vmcnt(" #N ")" ::: "memory")
#define BAR()    __builtin_amdgcn_s_barrier()

template<typename OutT>
__global__ __launch_bounds__(512, 2) void gemm256_kernel(
    const u16* __restrict__ A, const u16* __restrict__ Bt,
    OutT* __restrict__ C, int M, int N, int K)
{
    __shared__ __align__(16) u16 As0[16384];   // [256 rows][64], buf0
    __shared__ __align__(16) u16 As1[16384];   // buf1
    __shared__ __align__(16) u16 Bs0[16384];
    __shared__ __align__(16) u16 Bs1[16384];

    // bijective XCD swizzle (nwg % 8 == 0 for both call sites)
    const int nwg = gridDim.x;
    const int bid = blockIdx.x;
    const int cpx = nwg >> 3;
    const int swz = (bid & 7) * cpx + (bid >> 3);
    const int NX  = N >> 8;
    const int m0  = (swz / NX) << 8;
    const int n0  = (swz % NX) << 8;

    const int tid  = threadIdx.x;
    const int lane = tid & 63;
    const int wave = tid >> 6;
    const int wrow = wave >> 2;          // 0..1
    const int wcol = wave & 3;           // 0..3
    const int l16  = lane & 15;
    const int quad = lane >> 4;
    const int axor = l16 & 7;

    const int srow8  = lane >> 3;
    const int schunk = (lane & 7) ^ srow8;      // pre-swizzled DMA source chunk
    const u16* Ag = A  + (size_t)(m0 + wave*8 + srow8)*K + schunk*8;
    const u16* Bg = Bt + (size_t)(n0 + wave*8 + srow8)*K + schunk*8;

    f32x4 acc[8][4];
    #pragma unroll
    for (int i = 0; i < 8; i++)
        #pragma unroll
        for (int j = 0; j < 4; j++) acc[i][j] = (f32x4){0.f,0.f,0.f,0.f};
    bf16x8 af[4], bf[4];

    // prologue: tile0 full (B then A-MH0 then A-MH1), tile1 B rows 0-127.
    STG256(Bs0, Bg,   0, 0); STG256(Bs0, Bg,  64, 0);
    STG256(Bs0, Bg, 128, 0); STG256(Bs0, Bg, 192, 0);
    STG256(As0, Ag,   0, 0); STG256(As0, Ag, 128, 0);   // MH0 rows
    STG256(As0, Ag,  64, 0); STG256(As0, Ag, 192, 0);   // MH1 rows
    STG256(Bs1, Bg,   0, 1); STG256(Bs1, Bg,  64, 1);
    WAITV(4);                 // B0 + A0-MH0 landed; {A0-MH1, B1c01} in flight
    BAR();

    const int NT2 = K >> 7;          // K/128 double-K-tile iterations
    for (int t = 0; t < NT2; ++t) {
        const int T1 = 2*t+1, T2 = 2*t+2, T3 = 2*t+3;
        const bool nl = (t < NT2-1);

        // ---- phase 1: buf0 (mh0,kk0) ----
        g256_ld_b<0>(Bs0, bf, wcol, l16, quad, axor);
        g256_ld_a<0,0>(As0, af, wrow, l16, quad, axor);
        STG256(Bs1, Bg, 128, T1); STG256(Bs1, Bg, 192, T1);
        BAR();
        g256_mfma<0>(af, bf, acc);
        WAITV(4);                    // retires prev-ph7 A0-MH1 (read in ph2)
        BAR();

        // ---- phase 2: buf0 (mh1,kk0), reuse B ----
        g256_ld_a<1,0>(As0, af, wrow, l16, quad, axor);
        STG256(As1, Ag, 0, T1); STG256(As1, Ag, 128, T1);   // A1 MH0 rows
        BAR();
        g256_mfma<1>(af, bf, acc);
        BAR();

        // ---- phase 3: buf0 (mh0,kk1) ----
        g256_ld_b<1>(Bs0, bf, wcol, l16, quad, axor);
        g256_ld_a<0,1>(As0, af, wrow, l16, quad, axor);
        STG256(As1, Ag, 64, T1); STG256(As1, Ag, 192, T1);  // A1 MH1 rows
        BAR();
        g256_mfma<0>(af, bf, acc);
        BAR();

        // ---- phase 4: buf0 (mh1,kk1) ----
        g256_ld_a<1,1>(As0, af, wrow, l16, quad, axor);
        if (nl) { STG256(Bs0, Bg, 0, T2); STG256(Bs0, Bg, 64, T2); }
        BAR();
        g256_mfma<1>(af, bf, acc);
        if (nl) { WAITV(4); }        // retires B1(all) + A1-MH0 (read in ph5)
        else    { WAITV(0); }        // final drain: buf1 fully ready
        BAR();

        // ---- phase 5: buf1 (mh0,kk0) ----
        g256_ld_b<0>(Bs1, bf, wcol, l16, quad, axor);
        g256_ld_a<0,0>(As1, af, wrow, l16, quad, axor);
        if (nl) { STG256(Bs0, Bg, 128, T2); STG256(Bs0, Bg, 192, T2); }
        BAR();
        g256_mfma<0>(af, bf, acc);
        WAITV(4);                    // retires A1-MH1 (read in ph6); no-op on last iter
        BAR();

        // ---- phase 6: buf1 (mh1,kk0) ----
        g256_ld_a<1,0>(As1, af, wrow, l16, quad, axor);
        if (nl) { STG256(As0, Ag, 0, T2); STG256(As0, Ag, 128, T2); }
        BAR();
        g256_mfma<1>(af, bf, acc);
        BAR();

        // ---- phase 7: buf1 (mh0,kk1) ----
        g256_ld_b<1>(Bs1, bf, wcol, l16, quad, axor);
        g256_ld_a<0,1>(As1, af, wrow, l16, quad, axor);
        if (nl) { STG256(As0, Ag, 64, T2); STG256(As0, Ag, 192, T2); }
        BAR();
        g256_mfma<0>(af, bf, acc);
        BAR();

        // ---- phase 8: buf1 (mh1,kk1) ----
        g256_ld_a<1,1>(As1, af, wrow, l16, quad, axor);
        if (nl) { STG256(Bs1, Bg, 0, T3); STG256(Bs1, Bg, 64, T3); }
        BAR();
        g256_mfma<1>(af, bf, acc);
        WAITV(4);                    // retires B0'(all) + A0'-MH0 (read next ph1)
        BAR();
    }

    #pragma unroll
    for (int ii = 0; ii < 8; ii++) {
        const int rbase = m0 + wrow*128 + ii*16 + quad*4;
        #pragma unroll
        for (int j = 0; j < 4; j++) {
            const int col = n0 + wcol*64 + j*16 + l16;
            #pragma unroll
            for (int r = 0; r < 4; r++) {
                const float v = acc[ii][j][r];
                if constexpr (sizeof(OutT) == 2)
                    ((u16*)C)[(size_t)(rbase + r)*N + col] = f2bf(v);
                else
                    ((float*)C)[(size_t)(rbase + r)*N + col] = v;
            }
        }
    }
}

#undef STG256

// ---------------------------------------------------------------------------
// Fused RoPE (blocks 0..4095) + V-transpose (4096..4607).
// ---------------------------------------------------------------------------
__global__ __launch_bounds__(256) void ropevt_kernel(
    const u16* __restrict__ raw, u16* __restrict__ qb,
    u16* __restrict__ kbf, u16* __restrict__ vtt)
{
    __shared__ u16 T[32*264];
    const int bx  = blockIdx.x;
    const int tid = threadIdx.x;

    if (bx < BT) {
        const int r   = bx;
        const int pos = r & (SEQ-1);
        const u16* row = raw + (size_t)r * 4096;
        const float LOG1E4 = 9.210340371976184f;

        #pragma unroll
        for (int p = tid; p < 1024; p += 256) {   // q pairs
            const int n = p >> 7, j = p & 127;
            const float lo = bf2f(row[n*256 + j]);
            const float hi = bf2f(row[n*256 + j + 128]);
            const float inv = __expf(-LOG1E4 * (float)j * (1.0f/128.0f));
            float s, c; sincosf((float)pos * inv, &s, &c);
            qb[((size_t)r*N_Q + n)*HEAD_DIM + j]       = f2bf((lo*c - hi*s) * 0.0625f);
            qb[((size_t)r*N_Q + n)*HEAD_DIM + j + 128] = f2bf((hi*c + lo*s) * 0.0625f);
        }
        #pragma unroll
        for (int p = tid; p < 512; p += 256) {    // k pairs
            const int n = p >> 7, j = p & 127;
            const float lo = bf2f(row[2048 + n*256 + j]);
            const float hi = bf2f(row[2048 + n*256 + j + 128]);
            const float inv = __expf(-LOG1E4 * (float)j * (1.0f/128.0f));
            float s, c; sincosf((float)pos * inv, &s, &c);
            kbf[((size_t)r*N_KV + n)*HEAD_DIM + j]       = f2bf(lo*c - hi*s);
            kbf[((size_t)r*N_KV + n)*HEAD_DIM + j + 128] = f2bf(hi*c + lo*s);
        }
        return;
    }

    {
        const int blk = bx - BT;
        const int sc  = blk & 63;
        const int bk  = blk >> 6;
        const int b   = bk >> 2, kh = bk & 3;

        const u16* rrow = raw + (size_t)(b*SEQ + sc*32)*4096 + 3072 + kh*256;
        {
            const int s = tid >> 3;
            #pragma unroll
            for (int it = 0; it < 4; it++) {
                const int seg = (tid & 7) + it*8;
                *(uint4*)&T[s*264 + seg*8] = *(const uint4*)(rrow + (size_t)s*4096 + seg*8);
            }
        }
        __syncthreads();
        u16* out = vtt + (size_t)blk*8192;
        #pragma unroll
        for (int it = 0; it < 4; it++) {
            const int o = tid + it*256;
            const int h = o >> 2, ss = o & 3;
            u16 tmp[8];
            #pragma unroll
            for (int j = 0; j < 8; j++) tmp[j] = T[(ss*8 + j)*264 + h];
            *(uint4*)(out + h*32 + ((ss ^ (h & 3))*8)) = *(const uint4*)tmp;
        }
    }
}

// ---------------------------------------------------------------------------
// MFMA flash attention (R9): double-buffered K/V/P, issue-early/write-late
// staging, raw barriers with counted waits. 2 barriers/tile (was 3 with full
// drains); V-DMA covered by a full tile of compute, K staged global->reg
// before QK^T and reg->LDS after softmax (T14). Distinct __shared__ arrays
// for compile-time identity (R1 lesson). Tile count is always EVEN
// (tb % 64 == 0 => count = tb/32+2 or 34), so the loop is 2x unrolled with
// no tail. LDS 76.9 KB -> 2 blocks/CU.
//
// Barrier ledger per step (cur=c, nxt=n):
//   stage: V-DMA -> Vs{n} (vmcnt), K global->kreg (vmcnt, consumer later)
//   QK^T reads Ks{c} (staged >=1 barrier ago, drained by prev end-wait)
//   softmax writes Ps{c} (reads of Ps{c} ended 2 barriers ago)
//   kreg -> Ks{n} ds_write (reads of Ks{n} ended 2 barriers ago)
//   lgkmcnt(0) + BAR:  Ps{c}, Ks{n} writes visible
//   PV reads Ps{c}, Vs{c} (Vs{c} DMA drained at prev end-wait)
//   vmcnt(0) + BAR:    Vs{n} DMA (issued a full tile ago) + kreg retired
// ---------------------------------------------------------------------------
#define AQT 64

#define ATTN_STEP(KSc, VSc, PSc, KSn, VSn, ST, NX)                              \
{                                                                               \
    uint4 kreg[4];                                                              \
    if (NX) {                                                                   \
        const u16* vtile = vbase + (size_t)((ST)+32)*HEAD_DIM;                  \
        _Pragma("unroll")                                                       \
        for (int c4 = 0; c4 < 4; c4++) {                                        \
            const int off = wave*2048 + c4*512;                                 \
            __builtin_amdgcn_global_load_lds(                                   \
                (const __attribute__((address_space(1))) unsigned int*)(vtile + off + lane*8), \
                (__attribute__((address_space(3))) unsigned int*)&VSn[off],     \
                16, 0, 0);                                                      \
        }                                                                       \
        const u16* krow = kbase + (size_t)((ST)+32 + ks)*(N_KV*HEAD_DIM);       \
        _Pragma("unroll")                                                       \
        for (int it = 0; it < 4; it++)                                          \
            kreg[it] = *(const uint4*)(krow + ((tid & 7) + it*8)*8);            \
    }                                                                           \
    f32x4 sc[2];                                                                \
    _Pragma("unroll")                                                           \
    for (int sf = 0; sf < 2; sf++) {                                            \
        f32x4 a = (f32x4){0.f,0.f,0.f,0.f};                                     \
        const u16* kr = &KSc[(sf*16 + l16)*264 + quad*8];                       \
        _Pragma("unroll")                                                       \
        for (int cc = 0; cc < 8; cc++)                                          \
            a = __builtin_amdgcn_mfma_f32_16x16x32_bf16(                        \
                    qf[cc], *(const bf16x8*)(kr + cc*32), a, 0, 0, 0);          \
        sc[sf] = a;                                                             \
    }                                                                           \
    _Pragma("unroll")                                                           \
    for (int sf = 0; sf < 2; sf++) {                                            \
        const int sg = (ST) + sf*16 + l16;                                      \
        _Pragma("unroll")                                                       \
        for (int r = 0; r < 4; r++) {                                           \
            const int tg = tb + wave*16 + quad*4 + r;                           \
            const float e1 = __expf(sc[sf][r] * 0.04f);                         \
            float p = __expf(-100.0f / (e1 + 1.0f));                            \
            const bool ok = (sg <= tg) && (tg - sg < WINDOW);                   \
            p = ok ? p : 0.0f;                                                  \
            lpart[r] += p;                                                      \
            PSc[(wave*16 + quad*4 + r)*40 + sf*16 + l16] = f2bf(p);             \
        }                                                                       \
    }                                                                           \
    if (NX) {                                                                   \
        _Pragma("unroll")                                                       \
        for (int it = 0; it < 4; it++)                                          \
            *(uint4*)&KSn[ks*264 + ((tid & 7) + it*8)*8] = kreg[it];            \
    }                                                                           \
    asm volatile("s_waitcnt lgkmcnt(0)" ::: "memory");                          \
    __builtin_amdgcn_s_barrier();                                               \
    bf16x8 ap[4];                                                               \
    _Pragma("unroll")                                                           \
    for (int i = 0; i < 4; i++)                                                 \
        ap[i] = *(const bf16x8*)&PSc[(i*16 + l16)*40 + quad*8];                 \
    _Pragma("unroll")                                                           \
    for (int j = 0; j < 4; j++) {                                               \
        const int hr = wave*64 + j*16 + l16;                                    \
        const bf16x8 bv = *(const bf16x8*)&VSc[hr*32 + ((quad ^ (l16 & 3))*8)]; \
        _Pragma("unroll")                                                       \
        for (int i = 0; i < 4; i++)                                             \
            o[i][j] = __builtin_amdgcn_mfma_f32_16x16x32_bf16(ap[i], bv, o[i][j], 0, 0, 0); \
    }                                                                           \
    if (NX) { asm volatile("s_waitcnt vmcnt(0)" ::: "memory"); }                \
    __builtin_amdgcn_s_barrier();                                               \
}

__global__ __launch_bounds__(256) void attn_mfma_kernel(
    const u16* __restrict__ qb, const u16* __restrict__ kb,
    const u16* __restrict__ vtt, u16* __restrict__ ao)
{
    __shared__ u16 Ks0[32*264];   // K[s][d], pad 264 (16,896 B each)
    __shared__ u16 Ks1[32*264];
    __shared__ u16 Vs0[256*32];   // V^T swizzled (16,384 B each, DMA target)
    __shared__ u16 Vs1[256*32];
    __shared__ u16 Ps0[64*40];    // P[t][s], pad 40 (5,120 B each)
    __shared__ u16 Ps1[64*40];
    __shared__ float lsum[64];

    const int qh = blockIdx.y;
    const int kh = qh >> 1;
    const int bx = ((blockIdx.y >> 2) & 1) ? (gridDim.x - 1 - (int)blockIdx.x)
                                           : (int)blockIdx.x;
    const int t0 = bx * AQT;
    const int b  = t0 >> 11;
    const int tb = t0 & (SEQ-1);
    const int tid  = threadIdx.x;
    const int wave = tid >> 6;
    const int lane = tid & 63;
    const int l16  = lane & 15;
    const int quad = lane >> 4;
    const int ks   = tid >> 3;          // K-staging row (0..31)

    bf16x8 qf[8];
    {
        const u16* qrow = qb + ((size_t)(t0 + wave*16 + l16)*N_Q + qh)*HEAD_DIM + quad*8;
        #pragma unroll
        for (int c = 0; c < 8; c++) qf[c] = *(const bf16x8*)(qrow + c*32);
    }

    f32x4 o[4][4];
    #pragma unroll
    for (int i = 0; i < 4; i++)
        #pragma unroll
        for (int j = 0; j < 4; j++) o[i][j] = (f32x4){0.f,0.f,0.f,0.f};
    float lpart[4] = {0.f, 0.f, 0.f, 0.f};

    int s_begin = tb - (WINDOW-1); if (s_begin < 0) s_begin = 0;
    const int st0 = s_begin & ~31;

    const u16* kbase = kb  + ((size_t)(b*SEQ)*N_KV + kh)*HEAD_DIM;
    const u16* vbase = vtt + ((size_t)(b*N_KV + kh)*SEQ)*HEAD_DIM;

    // prologue: stage tile st0 -> buf0 (V DMA + K direct)
    {
        const u16* vtile = vbase + (size_t)st0*HEAD_DIM;
        #pragma unroll
        for (int c4 = 0; c4 < 4; c4++) {
            const int off = wave*2048 + c4*512;
            __builtin_amdgcn_global_load_lds(
                (const __attribute__((address_space(1))) unsigned int*)(vtile + off + lane*8),
                (__attribute__((address_space(3))) unsigned int*)&Vs0[off],
                16, 0, 0);
        }
        const u16* krow = kbase + (size_t)(st0 + ks)*(N_KV*HEAD_DIM);
        #pragma unroll
        for (int it = 0; it < 4; it++) {
            const int seg = (tid & 7) + it*8;
            *(uint4*)&Ks0[ks*264 + seg*8] = *(const uint4*)(krow + seg*8);
        }
    }
    __syncthreads();   // full drain once

    // tile count is always even: process pairs (buf0 then buf1)
    for (int st = st0; st < tb + AQT; st += 64) {
        ATTN_STEP(Ks0, Vs0, Ps0, Ks1, Vs1, st, true);
        const bool nx2 = (st + 64 < tb + AQT);
        ATTN_STEP(Ks1, Vs1, Ps1, Ks0, Vs0, st + 32, nx2);
    }

    // row sums -> LDS (QK rows are wave-owned)
    #pragma unroll
    for (int r = 0; r < 4; r++) {
        float s = lpart[r];
        #pragma unroll
        for (int sh = 1; sh <= 8; sh <<= 1) s += __shfl_xor(s, sh, 64);
        if (l16 == 0) lsum[wave*16 + quad*4 + r] = s;
    }
    __syncthreads();

    #pragma unroll
    for (int i = 0; i < 4; i++) {
        #pragma unroll
        for (int r = 0; r < 4; r++) {
            const int rl  = i*16 + quad*4 + r;
            const float inv = 1.0f / (lsum[rl] + 1e-30f);
            u16* arow = ao + ((size_t)(t0 + rl)*N_Q + qh)*HEAD_DIM + wave*64 + l16;
            #pragma unroll
            for (int j = 0; j < 4; j++)
                arow[j*16] = f2bf(o[i][j][r] * inv);
        }
    }
}

// ---------------------------------------------------------------------------
extern "C" void kernel_launch(void* const* d_in, const int* in_sizes, int n_in,
                              void* d_out, int out_size, void* d_ws, size_t ws_size,
                              hipStream_t stream)
{
    const float* x  = (const float*)d_in[0];
    // d_in[1] = attention_mask: exactly causal(tril) -> not needed.
    const float* Wq = (const float*)d_in[2];
    const float* Wk = (const float*)d_in[3];
    const float* Wv = (const float*)d_in[4];
    const float* Wo = (const float*)d_in[5];
    float* out = (float*)d_out;

    char* w = (char*)d_ws;
    u16* qbuf = (u16*)(w);                     // 16,777,216
    u16* kbuf = (u16*)(w +  16777216ull);      //  8,388,608
    u16* vtt  = (u16*)(w +  25165824ull);      //  8,388,608
    u16* aob  = (u16*)(w +  33554432ull);      // 16,777,216
    u16* xb   = (u16*)(w +  50331648ull);      // 18,874,368
    u16* wt1  = (u16*)(w +  69206016ull);      // 18,874,368
    u16* wot  = (u16*)(w +  88080384ull);      //  9,437,184
    u16* raw  = (u16*)(w +  97517568ull);      // 33,554,432 (end ~131 MB)

    // 1) fused preprocessing
    prep_kernel<<<8064, 256, 0, stream>>>(x, Wq, Wk, Wv, Wo, xb, wt1, wot);

    // 2) QKV GEMM: 256x256 8-phase (R3 schedule, frozen), 256 blocks = 1/CU.
    gemm256_kernel<u16><<<(BT/256)*(4096/256), 512, 0, stream>>>(
        xb, wt1, raw, BT, 4096, HIDDEN);

    // 3) fused RoPE + V-transpose
    ropevt_kernel<<<BT + BATCH*N_KV*64, 256, 0, stream>>>(raw, qbuf, kbuf, vtt);

    // 4) attention (double-buffered)
    attn_mfma_kernel<<<dim3(BT/AQT, N_Q), 256, 0, stream>>>(qbuf, kbuf, vtt, aob);

    // 5) output GEMM: 16x9 = 144 blocks (cpx=18, bijective swizzle holds).
    gemm256_kernel<float><<<(BT/256)*(HIDDEN/256), 512, 0, stream>>>(
        aob, wot, out, BT, HIDDEN, N_Q*HEAD_DIM);
}